// Round 5
// baseline (124.670 us; speedup 1.0000x reference)
//
#include <hip/hip_runtime.h>
#include <hip/hip_bf16.h>

#define HDIM 256
#define LDIM 384
#define BDIM 2
#define ADIM 14
#define H2 (HDIM / 2)

typedef __attribute__((ext_vector_type(8))) short bf16x8;
typedef __attribute__((ext_vector_type(4))) float f32x4;

static __device__ __forceinline__ unsigned pack_bf16(float x, float y) {
    __hip_bfloat162 t = __float22bfloat162_rn(make_float2(x, y));  // x -> low 16
    return *reinterpret_cast<unsigned*>(&t);
}

static __device__ __forceinline__ bf16x8 cvt8(float4 a, float4 b) {
    union { unsigned u[4]; bf16x8 v; } r;
    r.u[0] = pack_bf16(a.x, a.y); r.u[1] = pack_bf16(a.z, a.w);
    r.u[2] = pack_bf16(b.x, b.y); r.u[3] = pack_bf16(b.z, b.w);
    return r.v;
}

// ---------------------------------------------------------------------------
// Kernel 1 (MFMA): C(512c x 768rows) = [Wx;Ux](512x256) x h^T, bf16 inputs,
// fp32 accum. One wave per 32c x 32row tile; grid (16 c-tiles, 24 row-tiles).
// Outputs:
//   c<256:  hw[b][i][c] fp32 (float4 store + Wx_b)
//   c>=256: huP[b][j][h2] bf16-pair packed, J-MAJOR (uint2 stores)
// ---------------------------------------------------------------------------
__global__ __launch_bounds__(64) void k_gemm(
    const float* __restrict__ h,
    const float* __restrict__ Wx_w, const float* __restrict__ Wx_b,
    const float* __restrict__ Ux_w, const float* __restrict__ Ux_b,
    float* __restrict__ hw, unsigned* __restrict__ huP)
{
    const int lane = threadIdx.x;
    const int n = lane & 15;             // D-col: row index within row-tile
    const int quad = lane >> 4;

    const int c0   = blockIdx.x * 32;    // channel base (0..480), within Wx or Ux
    const int row0 = blockIdx.y * 32;    // global row base (0..736), within one b

    const float* __restrict__ wbase = (c0 < HDIM) ? &Wx_w[c0 * HDIM]
                                                  : &Ux_w[(c0 - HDIM) * HDIM];
    const float* __restrict__ wl0 = wbase + (n) * HDIM + quad * 8;
    const float* __restrict__ wl1 = wbase + (16 + n) * HDIM + quad * 8;
    const float* __restrict__ hl0 = h + (row0 + n) * HDIM + quad * 8;
    const float* __restrict__ hl1 = h + (row0 + 16 + n) * HDIM + quad * 8;

    f32x4 acc00 = {0,0,0,0}, acc01 = {0,0,0,0}, acc10 = {0,0,0,0}, acc11 = {0,0,0,0};

    #pragma unroll 4
    for (int kc = 0; kc < 8; ++kc) {
        const int ko = kc * 32;
        const bf16x8 a0 = cvt8(*(const float4*)(wl0 + ko), *(const float4*)(wl0 + ko + 4));
        const bf16x8 a1 = cvt8(*(const float4*)(wl1 + ko), *(const float4*)(wl1 + ko + 4));
        const bf16x8 b0 = cvt8(*(const float4*)(hl0 + ko), *(const float4*)(hl0 + ko + 4));
        const bf16x8 b1 = cvt8(*(const float4*)(hl1 + ko), *(const float4*)(hl1 + ko + 4));
        acc00 = __builtin_amdgcn_mfma_f32_16x16x32_bf16(a0, b0, acc00, 0, 0, 0);
        acc01 = __builtin_amdgcn_mfma_f32_16x16x32_bf16(a0, b1, acc01, 0, 0, 0);
        acc10 = __builtin_amdgcn_mfma_f32_16x16x32_bf16(a1, b0, acc10, 0, 0, 0);
        acc11 = __builtin_amdgcn_mfma_f32_16x16x32_bf16(a1, b1, acc11, 0, 0, 0);
    }

    const int grow0 = row0 + n;
    const int grow1 = row0 + 16 + n;
    const int b = row0 / LDIM;           // uniform per block
    const int i0 = grow0 - b * LDIM, i1 = grow1 - b * LDIM;

    if (c0 < HDIM) {
        #pragma unroll
        for (int ct = 0; ct < 2; ++ct) {
            const int cb = c0 + ct * 16 + quad * 4;
            const float4 bias = *(const float4*)&Wx_b[cb];
            const f32x4 aR0 = ct ? acc10 : acc00;
            const f32x4 aR1 = ct ? acc11 : acc01;
            *(float4*)&hw[grow0 * HDIM + cb] =
                make_float4(aR0[0] + bias.x, aR0[1] + bias.y, aR0[2] + bias.z, aR0[3] + bias.w);
            *(float4*)&hw[grow1 * HDIM + cb] =
                make_float4(aR1[0] + bias.x, aR1[1] + bias.y, aR1[2] + bias.z, aR1[3] + bias.w);
        }
    } else {
        unsigned* __restrict__ hub = &huP[b * LDIM * H2];   // [j][h2]
        #pragma unroll
        for (int ct = 0; ct < 2; ++ct) {
            const int ch = (c0 - HDIM) + ct * 16 + quad * 4;   // multiple of 4
            const float4 bias = *(const float4*)&Ux_b[ch];
            const f32x4 aR0 = ct ? acc10 : acc00;
            const f32x4 aR1 = ct ? acc11 : acc01;
            const int h2 = ch >> 1;                            // even -> 8B aligned
            *(uint2*)&hub[i0 * H2 + h2] = make_uint2(
                pack_bf16(aR0[0] + bias.x, aR0[1] + bias.y),
                pack_bf16(aR0[2] + bias.z, aR0[3] + bias.w));
            *(uint2*)&hub[i1 * H2 + h2] = make_uint2(
                pack_bf16(aR1[0] + bias.x, aR1[1] + bias.y),
                pack_bf16(aR1[2] + bias.z, aR1[3] + bias.w));
        }
    }
}

// ---------------------------------------------------------------------------
// Kernel 2: one block per (b,i). gate = relu(hw_i + hu_j) @ Tx_w^T via MFMA.
// hu is staged per-kc into a single 24KB LDS slab [384 j][16 h2] with
// reg-staged prefetch (loads for kc+1 issued before compute of kc, ds_write
// after the barrier). A-frag = one ds_read_b128 per (kc,tile).
// LDS total ~41KB -> 3 blocks/CU preserved. Math order identical to round 3.
// ---------------------------------------------------------------------------
__global__ __launch_bounds__(384, 5) void k_main(
    const float* __restrict__ hw, const unsigned* __restrict__ huP,
    const float* __restrict__ X, const int* __restrict__ mask,
    const float* __restrict__ Tx_w, const float* __restrict__ Tx_b,
    float* __restrict__ out)
{
    __shared__ unsigned TxP[16 * 130];             // [n][k2] bf16-pairs
    __shared__ __align__(16) unsigned hu_s[LDIM * 16];  // [j][16 h2] slab, 24576 B
    __shared__ float m_lds[LDIM];
    __shared__ float part2[24 * 16 * 4];
    __shared__ float part_m[24];

    const int i = blockIdx.x, b = blockIdx.y;
    const int tid = threadIdx.x;
    const int w = tid >> 6;              // wave 0..5
    const int lane = tid & 63;
    const int n = lane & 15;             // a-column / A-row-within-tile
    const int quad = lane >> 4;

    const unsigned* __restrict__ hub = &huP[b * LDIM * H2];  // [j][h2]

    // ---- prologue: issue slab-0 loads (hide under TxP packing)
    uint4 st[4];
    #pragma unroll
    for (int q = 0; q < 4; ++q) {
        const int c = tid + q * 384;     // chunk: j = c>>2, part = c&3
        st[q] = *(const uint4*)&hub[(c >> 2) * H2 + (c & 3) * 4];
    }

    // ---- setup: Tx_w -> bf16 packed LDS; mask -> LDS
    for (int idx = tid; idx < 16 * 128; idx += 384) {
        const int nn = idx >> 7, k2 = idx & 127;
        unsigned v = 0;
        if (nn < ADIM) {
            const float2 tw = *(const float2*)&Tx_w[nn * HDIM + 2 * k2];
            v = pack_bf16(tw.x, tw.y);
        }
        TxP[nn * 130 + k2] = v;
    }
    m_lds[tid] = (float)mask[b * LDIM + tid];

    #pragma unroll
    for (int q = 0; q < 4; ++q) {
        const int c = tid + q * 384;
        *(uint4*)&hu_s[c * 4] = st[q];
    }
    __syncthreads();

    const float* __restrict__ hwrow = &hw[(b * LDIM + i) * HDIM];

    f32x4 acc[4];
    #pragma unroll
    for (int t = 0; t < 4; ++t) acc[t] = (f32x4){0.f, 0.f, 0.f, 0.f};

    #pragma unroll
    for (int kc = 0; kc < 8; ++kc) {
        // prefetch next slab into registers (L2 latency hides under compute)
        if (kc < 7) {
            #pragma unroll
            for (int q = 0; q < 4; ++q) {
                const int c = tid + q * 384;
                st[q] = *(const uint4*)&hub[(c >> 2) * H2 + (kc + 1) * 16 + (c & 3) * 4];
            }
        }

        // B-frag (shared across the 4 tiles): Tx_w[n][kc*32+quad*8 .. +7]
        union { unsigned u[4]; bf16x8 v; } bu;
        const int bofs = n * 130 + kc * 16 + quad * 4;
        *(uint2*)&bu.u[0] = *(const uint2*)&TxP[bofs];
        *(uint2*)&bu.u[2] = *(const uint2*)&TxP[bofs + 2];
        // hw values for this lane's k-slice (L1-resident row, quad-broadcast)
        const float4 hwa = *(const float4*)(hwrow + kc * 32 + quad * 8);
        const float4 hwb = *(const float4*)(hwrow + kc * 32 + quad * 8 + 4);
        const float hv[8] = {hwa.x, hwa.y, hwa.z, hwa.w, hwb.x, hwb.y, hwb.z, hwb.w};

        #pragma unroll
        for (int t = 0; t < 4; ++t) {
            union { uint4 q; unsigned u[4]; } ar;
            ar.q = *(const uint4*)&hu_s[((w * 64 + t * 16 + n) * 16 + quad * 4)];
            union { unsigned u[4]; bf16x8 v; } au;
            #pragma unroll
            for (int d = 0; d < 4; ++d) {
                const unsigned pk = ar.u[d];
                const float lo = __uint_as_float(pk << 16);
                const float hi = __uint_as_float(pk & 0xffff0000u);
                const float t0 = fmaxf(hv[2 * d] + lo, 0.f);
                const float t1 = fmaxf(hv[2 * d + 1] + hi, 0.f);
                au.u[d] = pack_bf16(t0, t1);
            }
            acc[t] = __builtin_amdgcn_mfma_f32_16x16x32_bf16(au.v, bu.v, acc[t], 0, 0, 0);
        }

        __syncthreads();                 // all waves done reading hu_s
        if (kc < 7) {
            #pragma unroll
            for (int q = 0; q < 4; ++q) {
                const int c = tid + q * 384;
                *(uint4*)&hu_s[c * 4] = st[q];
            }
            __syncthreads();             // slab kc+1 visible to all
        }
    }

    // ---- epilogue: per-lane partial sums over its 16 j's (a = n)
    float s1 = 0.f, s2x = 0.f, s2y = 0.f, s2z = 0.f, pm = 0.f;
    if (n < ADIM) {
        const float txb = Tx_b[n];
        #pragma unroll
        for (int t = 0; t < 4; ++t) {
            #pragma unroll
            for (int r = 0; r < 4; ++r) {
                const int jd = (w * 4 + t) * 16 + quad * 4 + r;
                const float m = m_lds[jd];
                const float g = acc[t][r] + txb;
                const float mg = m * g;
                const float* __restrict__ Xp = &X[((b * LDIM + jd) * ADIM + n) * 3];
                s1 += mg;
                s2x = fmaf(mg, Xp[0], s2x);
                s2y = fmaf(mg, Xp[1], s2y);
                s2z = fmaf(mg, Xp[2], s2z);
                pm += m;
            }
        }
    }
    {
        f32x4 sv = {s2x, s2y, s2z, s1};
        *(f32x4*)&part2[((w * 4 + quad) * 16 + n) * 4] = sv;
    }
    if (n == 0) part_m[w * 4 + quad] = pm;
    __syncthreads();

    if (tid < 42) {
        const int a = tid / 3, c = tid % 3;
        float S2 = 0.f, S1 = 0.f, msum = 0.f;
        #pragma unroll 4
        for (int g = 0; g < 24; ++g) {
            const float* __restrict__ p = &part2[(g * 16 + a) * 4];
            S2 += p[c]; S1 += p[3]; msum += part_m[g];
        }
        const float denom = 1e-6f + msum;
        const int idx = ((b * LDIM + i) * ADIM + a) * 3 + c;
        const float xi = X[idx];
        float f = (xi * S1 - S2) / denom;
        f = fminf(fmaxf(f, -20.f), 20.f);
        out[idx] = xi + f;
    }
}

extern "C" void kernel_launch(void* const* d_in, const int* in_sizes, int n_in,
                              void* d_out, int out_size, void* d_ws, size_t ws_size,
                              hipStream_t stream) {
    (void)in_sizes; (void)n_in; (void)out_size; (void)ws_size;
    const float* h    = (const float*)d_in[0];
    const float* X    = (const float*)d_in[1];
    const int*   mask = (const int*)  d_in[2];
    const float* Wx_w = (const float*)d_in[3];
    const float* Wx_b = (const float*)d_in[4];
    const float* Ux_w = (const float*)d_in[5];
    const float* Ux_b = (const float*)d_in[6];
    const float* Tx_w = (const float*)d_in[7];
    const float* Tx_b = (const float*)d_in[8];
    float* out = (float*)d_out;

    float*    hw  = (float*)d_ws;                         // B*L*H fp32
    unsigned* huP = (unsigned*)(hw + BDIM * LDIM * HDIM); // B*L*H2 packed bf16 pairs (j-major)

    k_gemm<<<dim3(16, 24), dim3(64), 0, stream>>>(h, Wx_w, Wx_b, Ux_w, Ux_b, hw, huP);
    k_main<<<dim3(LDIM, BDIM), 384, 0, stream>>>(hw, huP, X, mask, Tx_w, Tx_b, out);
}

// Round 7
// 94.898 us; speedup vs baseline: 1.3137x; 1.3137x over previous
//
#include <hip/hip_runtime.h>
#include <hip/hip_bf16.h>

#define HDIM 256
#define LDIM 384
#define BDIM 2
#define ADIM 14
#define H2 (HDIM / 2)

typedef __attribute__((ext_vector_type(8))) short bf16x8;
typedef __attribute__((ext_vector_type(4))) float f32x4;

static __device__ __forceinline__ unsigned pack_bf16(float x, float y) {
    __hip_bfloat162 t = __float22bfloat162_rn(make_float2(x, y));  // x -> low 16
    return *reinterpret_cast<unsigned*>(&t);
}

static __device__ __forceinline__ bf16x8 cvt8(float4 a, float4 b) {
    union { unsigned u[4]; bf16x8 v; } r;
    r.u[0] = pack_bf16(a.x, a.y); r.u[1] = pack_bf16(a.z, a.w);
    r.u[2] = pack_bf16(b.x, b.y); r.u[3] = pack_bf16(b.z, b.w);
    return r.v;
}

// ---------------------------------------------------------------------------
// Kernel 1 (MFMA): C(512c x 768rows) = [Wx;Ux](512x256) x h^T, bf16 inputs,
// fp32 accum. One wave per 32c x 32row tile; grid (16 c-tiles, 24 row-tiles).
// Outputs (round-3 proven layout):
//   c<256:  hw[b][i][c] fp32 (float4 store + Wx_b)
//   c>=256: huP[b][h2][j] bf16-pair packed, H-MAJOR
// ---------------------------------------------------------------------------
__global__ __launch_bounds__(64) void k_gemm(
    const float* __restrict__ h,
    const float* __restrict__ Wx_w, const float* __restrict__ Wx_b,
    const float* __restrict__ Ux_w, const float* __restrict__ Ux_b,
    float* __restrict__ hw, unsigned* __restrict__ huP)
{
    const int lane = threadIdx.x;
    const int n = lane & 15;             // D-col: row index within row-tile
    const int quad = lane >> 4;

    const int c0   = blockIdx.x * 32;    // channel base (0..480), within Wx or Ux
    const int row0 = blockIdx.y * 32;    // global row base (0..736), within one b

    const float* __restrict__ wbase = (c0 < HDIM) ? &Wx_w[c0 * HDIM]
                                                  : &Ux_w[(c0 - HDIM) * HDIM];
    const float* __restrict__ wl0 = wbase + (n) * HDIM + quad * 8;
    const float* __restrict__ wl1 = wbase + (16 + n) * HDIM + quad * 8;
    const float* __restrict__ hl0 = h + (row0 + n) * HDIM + quad * 8;
    const float* __restrict__ hl1 = h + (row0 + 16 + n) * HDIM + quad * 8;

    f32x4 acc00 = {0,0,0,0}, acc01 = {0,0,0,0}, acc10 = {0,0,0,0}, acc11 = {0,0,0,0};

    #pragma unroll 4
    for (int kc = 0; kc < 8; ++kc) {
        const int ko = kc * 32;
        const bf16x8 a0 = cvt8(*(const float4*)(wl0 + ko), *(const float4*)(wl0 + ko + 4));
        const bf16x8 a1 = cvt8(*(const float4*)(wl1 + ko), *(const float4*)(wl1 + ko + 4));
        const bf16x8 b0 = cvt8(*(const float4*)(hl0 + ko), *(const float4*)(hl0 + ko + 4));
        const bf16x8 b1 = cvt8(*(const float4*)(hl1 + ko), *(const float4*)(hl1 + ko + 4));
        acc00 = __builtin_amdgcn_mfma_f32_16x16x32_bf16(a0, b0, acc00, 0, 0, 0);
        acc01 = __builtin_amdgcn_mfma_f32_16x16x32_bf16(a0, b1, acc01, 0, 0, 0);
        acc10 = __builtin_amdgcn_mfma_f32_16x16x32_bf16(a1, b0, acc10, 0, 0, 0);
        acc11 = __builtin_amdgcn_mfma_f32_16x16x32_bf16(a1, b1, acc11, 0, 0, 0);
    }

    const int grow0 = row0 + n;
    const int grow1 = row0 + 16 + n;
    const int b = row0 / LDIM;           // uniform per block
    const int i0 = grow0 - b * LDIM, i1 = grow1 - b * LDIM;

    if (c0 < HDIM) {
        #pragma unroll
        for (int ct = 0; ct < 2; ++ct) {
            const int cb = c0 + ct * 16 + quad * 4;
            const float4 bias = *(const float4*)&Wx_b[cb];
            const f32x4 aR0 = ct ? acc10 : acc00;
            const f32x4 aR1 = ct ? acc11 : acc01;
            *(float4*)&hw[grow0 * HDIM + cb] =
                make_float4(aR0[0] + bias.x, aR0[1] + bias.y, aR0[2] + bias.z, aR0[3] + bias.w);
            *(float4*)&hw[grow1 * HDIM + cb] =
                make_float4(aR1[0] + bias.x, aR1[1] + bias.y, aR1[2] + bias.z, aR1[3] + bias.w);
        }
    } else {
        // hu part: pack pairs along c (same lane holds c, c+1 in regs r, r+1)
        unsigned* __restrict__ hub = &huP[b * H2 * LDIM];
        #pragma unroll
        for (int ct = 0; ct < 2; ++ct) {
            const int ch = (c0 - HDIM) + ct * 16 + quad * 4;   // even
            const float4 bias = *(const float4*)&Ux_b[ch];
            const f32x4 aR0 = ct ? acc10 : acc00;
            const f32x4 aR1 = ct ? acc11 : acc01;
            const int h2 = ch >> 1;
            hub[(h2)     * LDIM + i0] = pack_bf16(aR0[0] + bias.x, aR0[1] + bias.y);
            hub[(h2 + 1) * LDIM + i0] = pack_bf16(aR0[2] + bias.z, aR0[3] + bias.w);
            hub[(h2)     * LDIM + i1] = pack_bf16(aR1[0] + bias.x, aR1[1] + bias.y);
            hub[(h2 + 1) * LDIM + i1] = pack_bf16(aR1[2] + bias.z, aR1[3] + bias.w);
        }
    }
}

// ---------------------------------------------------------------------------
// Kernel 2: one block per (b, i-pair). gate = relu(hw_i + hu_j) @ Tx_w^T via
// MFMA for TWO residues i0,i0+1 sharing every hu load (halves L2 traffic).
// Same per-output math order as round 3 (bit-identical results).
// Grid 384 blocks; stays fully co-resident even at 2 blocks/CU.
// ---------------------------------------------------------------------------
__global__ __launch_bounds__(384) void k_main(
    const float* __restrict__ hw, const unsigned* __restrict__ huP,
    const float* __restrict__ X, const int* __restrict__ mask,
    const float* __restrict__ Tx_w, const float* __restrict__ Tx_b,
    float* __restrict__ out)
{
    __shared__ unsigned TxP[16 * 130];     // [n][k2] bf16-pairs, stride 130
    __shared__ float m_lds[LDIM];
    __shared__ float part2[2][24 * 16 * 4]; // per-i: [g][a][{s2x,s2y,s2z,s1}]
    __shared__ float part_m[24];

    const int i0 = blockIdx.x * 2, b = blockIdx.y;
    const int tid = threadIdx.x;
    const int w = tid >> 6;              // wave 0..5
    const int lane = tid & 63;
    const int n = lane & 15;             // a-column / A-row-within-tile
    const int quad = lane >> 4;

    // ---- setup: Tx_w -> bf16 packed LDS; mask -> LDS
    for (int idx = tid; idx < 16 * 128; idx += 384) {
        const int nn = idx >> 7, k2 = idx & 127;
        unsigned v = 0;
        if (nn < ADIM) {
            const float2 tw = *(const float2*)&Tx_w[nn * HDIM + 2 * k2];
            v = pack_bf16(tw.x, tw.y);
        }
        TxP[nn * 130 + k2] = v;
    }
    m_lds[tid] = (float)mask[b * LDIM + tid];
    __syncthreads();

    const float* __restrict__ hwrow0 = &hw[(b * LDIM + i0) * HDIM];
    const float* __restrict__ hwrow1 = hwrow0 + HDIM;
    const unsigned* __restrict__ hub = &huP[b * H2 * LDIM];  // [h2][j]

    f32x4 acc0[4], acc1[4];
    #pragma unroll
    for (int t = 0; t < 4; ++t) {
        acc0[t] = (f32x4){0.f, 0.f, 0.f, 0.f};
        acc1[t] = (f32x4){0.f, 0.f, 0.f, 0.f};
    }

    const int jbase = w * 64 + n;        // A-side j for tile t: jbase + t*16

    #pragma unroll 2
    for (int kc = 0; kc < 8; ++kc) {
        // B-frag (shared across tiles and both i's)
        union { unsigned u[4]; bf16x8 v; } bu;
        const int bofs = n * 130 + kc * 16 + quad * 4;
        *(uint2*)&bu.u[0] = *(const uint2*)&TxP[bofs];
        *(uint2*)&bu.u[2] = *(const uint2*)&TxP[bofs + 2];
        // hw k-slices for both residues (L1-resident rows, quad-broadcast)
        const float4 h0a = *(const float4*)(hwrow0 + kc * 32 + quad * 8);
        const float4 h0b = *(const float4*)(hwrow0 + kc * 32 + quad * 8 + 4);
        const float4 h1a = *(const float4*)(hwrow1 + kc * 32 + quad * 8);
        const float4 h1b = *(const float4*)(hwrow1 + kc * 32 + quad * 8 + 4);
        const float hv0[8] = {h0a.x, h0a.y, h0a.z, h0a.w, h0b.x, h0b.y, h0b.z, h0b.w};
        const float hv1[8] = {h1a.x, h1a.y, h1a.z, h1a.w, h1b.x, h1b.y, h1b.z, h1b.w};
        const int h2base = kc * 16 + quad * 4;
        #pragma unroll
        for (int t = 0; t < 4; ++t) {
            const unsigned* __restrict__ hp = &hub[h2base * LDIM + jbase + t * 16];
            union { unsigned u[4]; bf16x8 v; } au0, au1;
            #pragma unroll
            for (int d = 0; d < 4; ++d) {
                const unsigned pk = hp[d * LDIM];          // hu load SHARED by i0,i1
                const float lo = __uint_as_float(pk << 16);
                const float hi = __uint_as_float(pk & 0xffff0000u);
                au0.u[d] = pack_bf16(fmaxf(hv0[2 * d] + lo, 0.f),
                                     fmaxf(hv0[2 * d + 1] + hi, 0.f));
                au1.u[d] = pack_bf16(fmaxf(hv1[2 * d] + lo, 0.f),
                                     fmaxf(hv1[2 * d + 1] + hi, 0.f));
            }
            acc0[t] = __builtin_amdgcn_mfma_f32_16x16x32_bf16(au0.v, bu.v, acc0[t], 0, 0, 0);
            acc1[t] = __builtin_amdgcn_mfma_f32_16x16x32_bf16(au1.v, bu.v, acc1[t], 0, 0, 0);
        }
    }

    // ---- epilogue: per-lane partial sums over its 16 j's (a = n), both i's.
    // X/mask values loaded once, used for both. Same accumulation order per
    // output as round 3 -> bit-identical results.
    float s1A = 0.f, s2xA = 0.f, s2yA = 0.f, s2zA = 0.f;
    float s1B = 0.f, s2xB = 0.f, s2yB = 0.f, s2zB = 0.f, pm = 0.f;
    if (n < ADIM) {
        const float txb = Tx_b[n];
        #pragma unroll
        for (int t = 0; t < 4; ++t) {
            #pragma unroll
            for (int r = 0; r < 4; ++r) {
                const int jd = (w * 4 + t) * 16 + quad * 4 + r;
                const float m = m_lds[jd];
                const float* __restrict__ Xp = &X[((b * LDIM + jd) * ADIM + n) * 3];
                const float x0 = Xp[0], x1 = Xp[1], x2 = Xp[2];
                const float mg0 = m * (acc0[t][r] + txb);
                s1A += mg0;
                s2xA = fmaf(mg0, x0, s2xA);
                s2yA = fmaf(mg0, x1, s2yA);
                s2zA = fmaf(mg0, x2, s2zA);
                const float mg1 = m * (acc1[t][r] + txb);
                s1B += mg1;
                s2xB = fmaf(mg1, x0, s2xB);
                s2yB = fmaf(mg1, x1, s2yB);
                s2zB = fmaf(mg1, x2, s2zB);
                pm += m;
            }
        }
    }
    {
        const int po = ((w * 4 + quad) * 16 + n) * 4;
        *(f32x4*)&part2[0][po] = (f32x4){s2xA, s2yA, s2zA, s1A};
        *(f32x4*)&part2[1][po] = (f32x4){s2xB, s2yB, s2zB, s1B};
    }
    if (n == 0) part_m[w * 4 + quad] = pm;
    __syncthreads();

    if (tid < 84) {
        const int ii = (tid >= 42) ? 1 : 0;
        const int r  = tid - ii * 42;
        const int a = r / 3, c = r % 3;
        float S2 = 0.f, S1 = 0.f, msum = 0.f;
        #pragma unroll 4
        for (int g = 0; g < 24; ++g) {
            const float* __restrict__ p = &part2[ii][(g * 16 + a) * 4];
            S2 += p[c]; S1 += p[3]; msum += part_m[g];
        }
        const float denom = 1e-6f + msum;
        const int idx = ((b * LDIM + i0 + ii) * ADIM + a) * 3 + c;
        const float xi = X[idx];
        float f = (xi * S1 - S2) / denom;
        f = fminf(fmaxf(f, -20.f), 20.f);
        out[idx] = xi + f;
    }
}

extern "C" void kernel_launch(void* const* d_in, const int* in_sizes, int n_in,
                              void* d_out, int out_size, void* d_ws, size_t ws_size,
                              hipStream_t stream) {
    (void)in_sizes; (void)n_in; (void)out_size; (void)ws_size;
    const float* h    = (const float*)d_in[0];
    const float* X    = (const float*)d_in[1];
    const int*   mask = (const int*)  d_in[2];
    const float* Wx_w = (const float*)d_in[3];
    const float* Wx_b = (const float*)d_in[4];
    const float* Ux_w = (const float*)d_in[5];
    const float* Ux_b = (const float*)d_in[6];
    const float* Tx_w = (const float*)d_in[7];
    const float* Tx_b = (const float*)d_in[8];
    float* out = (float*)d_out;

    float*    hw  = (float*)d_ws;                         // B*L*H fp32
    unsigned* huP = (unsigned*)(hw + BDIM * LDIM * HDIM); // B*(H/2)*L packed bf16 pairs (h-major)

    k_gemm<<<dim3(16, 24), dim3(64), 0, stream>>>(h, Wx_w, Wx_b, Ux_w, Ux_b, hw, huP);
    k_main<<<dim3(LDIM / 2, BDIM), 384, 0, stream>>>(hw, huP, X, mask, Tx_w, Tx_b, out);
}

// Round 8
// 93.471 us; speedup vs baseline: 1.3338x; 1.0153x over previous
//
#include <hip/hip_runtime.h>
#include <hip/hip_bf16.h>

#define HDIM 256
#define LDIM 384
#define BDIM 2
#define ADIM 14
#define H2 (HDIM / 2)

typedef __attribute__((ext_vector_type(8))) short bf16x8;
typedef __attribute__((ext_vector_type(4))) float f32x4;

static __device__ __forceinline__ unsigned pack_bf16(float x, float y) {
    __hip_bfloat162 t = __float22bfloat162_rn(make_float2(x, y));  // x -> low 16
    return *reinterpret_cast<unsigned*>(&t);
}

static __device__ __forceinline__ bf16x8 cvt8(float4 a, float4 b) {
    union { unsigned u[4]; bf16x8 v; } r;
    r.u[0] = pack_bf16(a.x, a.y); r.u[1] = pack_bf16(a.z, a.w);
    r.u[2] = pack_bf16(b.x, b.y); r.u[3] = pack_bf16(b.z, b.w);
    return r.v;
}

// ---------------------------------------------------------------------------
// Kernel 1 (MFMA): C(512c x 768rows) = [Wx;Ux](512x256) x h^T, bf16 inputs,
// fp32 accum. One wave per 32c x 32row tile; grid (16 c-tiles, 24 row-tiles).
// Outputs:
//   c<256:  hw[b][i][c] fp32 (float4 store + Wx_b)
//   c>=256: huP grouped-of-4 layout: huQ[(h2>>2)*L*4 + j*4 + (h2&3)]
//           (4 consecutive h2-pairs contiguous per j -> k_main dwordx4 loads)
// ---------------------------------------------------------------------------
__global__ __launch_bounds__(64) void k_gemm(
    const float* __restrict__ h,
    const float* __restrict__ Wx_w, const float* __restrict__ Wx_b,
    const float* __restrict__ Ux_w, const float* __restrict__ Ux_b,
    float* __restrict__ hw, unsigned* __restrict__ huP)
{
    const int lane = threadIdx.x;
    const int n = lane & 15;             // D-col: row index within row-tile
    const int quad = lane >> 4;

    const int c0   = blockIdx.x * 32;    // channel base (0..480), within Wx or Ux
    const int row0 = blockIdx.y * 32;    // global row base (0..736), within one b

    const float* __restrict__ wbase = (c0 < HDIM) ? &Wx_w[c0 * HDIM]
                                                  : &Ux_w[(c0 - HDIM) * HDIM];
    const float* __restrict__ wl0 = wbase + (n) * HDIM + quad * 8;
    const float* __restrict__ wl1 = wbase + (16 + n) * HDIM + quad * 8;
    const float* __restrict__ hl0 = h + (row0 + n) * HDIM + quad * 8;
    const float* __restrict__ hl1 = h + (row0 + 16 + n) * HDIM + quad * 8;

    f32x4 acc00 = {0,0,0,0}, acc01 = {0,0,0,0}, acc10 = {0,0,0,0}, acc11 = {0,0,0,0};

    #pragma unroll 4
    for (int kc = 0; kc < 8; ++kc) {
        const int ko = kc * 32;
        const bf16x8 a0 = cvt8(*(const float4*)(wl0 + ko), *(const float4*)(wl0 + ko + 4));
        const bf16x8 a1 = cvt8(*(const float4*)(wl1 + ko), *(const float4*)(wl1 + ko + 4));
        const bf16x8 b0 = cvt8(*(const float4*)(hl0 + ko), *(const float4*)(hl0 + ko + 4));
        const bf16x8 b1 = cvt8(*(const float4*)(hl1 + ko), *(const float4*)(hl1 + ko + 4));
        acc00 = __builtin_amdgcn_mfma_f32_16x16x32_bf16(a0, b0, acc00, 0, 0, 0);
        acc01 = __builtin_amdgcn_mfma_f32_16x16x32_bf16(a0, b1, acc01, 0, 0, 0);
        acc10 = __builtin_amdgcn_mfma_f32_16x16x32_bf16(a1, b0, acc10, 0, 0, 0);
        acc11 = __builtin_amdgcn_mfma_f32_16x16x32_bf16(a1, b1, acc11, 0, 0, 0);
    }

    const int grow0 = row0 + n;
    const int grow1 = row0 + 16 + n;
    const int b = row0 / LDIM;           // uniform per block
    const int i0 = grow0 - b * LDIM, i1 = grow1 - b * LDIM;

    if (c0 < HDIM) {
        #pragma unroll
        for (int ct = 0; ct < 2; ++ct) {
            const int cb = c0 + ct * 16 + quad * 4;
            const float4 bias = *(const float4*)&Wx_b[cb];
            const f32x4 aR0 = ct ? acc10 : acc00;
            const f32x4 aR1 = ct ? acc11 : acc01;
            *(float4*)&hw[grow0 * HDIM + cb] =
                make_float4(aR0[0] + bias.x, aR0[1] + bias.y, aR0[2] + bias.z, aR0[3] + bias.w);
            *(float4*)&hw[grow1 * HDIM + cb] =
                make_float4(aR1[0] + bias.x, aR1[1] + bias.y, aR1[2] + bias.z, aR1[3] + bias.w);
        }
    } else {
        // hu part: lane holds channels ch..ch+3 = h2-pairs h2, h2+1 -> one
        // uint2 per row into the grouped layout (8B-aligned: h2&3 in {0,2}).
        unsigned* __restrict__ hub = &huP[b * H2 * LDIM];
        #pragma unroll
        for (int ct = 0; ct < 2; ++ct) {
            const int ch = (c0 - HDIM) + ct * 16 + quad * 4;   // multiple of 4
            const float4 bias = *(const float4*)&Ux_b[ch];
            const f32x4 aR0 = ct ? acc10 : acc00;
            const f32x4 aR1 = ct ? acc11 : acc01;
            const int h2  = ch >> 1;
            const int blk = h2 >> 2, off = h2 & 3;             // off in {0,2}
            *(uint2*)&hub[(blk * LDIM + i0) * 4 + off] = make_uint2(
                pack_bf16(aR0[0] + bias.x, aR0[1] + bias.y),
                pack_bf16(aR0[2] + bias.z, aR0[3] + bias.w));
            *(uint2*)&hub[(blk * LDIM + i1) * 4 + off] = make_uint2(
                pack_bf16(aR1[0] + bias.x, aR1[1] + bias.y),
                pack_bf16(aR1[2] + bias.z, aR1[3] + bias.w));
        }
    }
}

// ---------------------------------------------------------------------------
// Kernel 2: one block per (b,i) — round-3 structure (768 blocks, 3/CU, no
// barriers in the loop). gate = relu(hw_i + hu_j) @ Tx_w^T via MFMA.
// A-frag hu loads: ONE dwordx4 per (kc,tile) from the grouped layout
// (was 4 scalar dwords at stride LDIM) -> 32 VMEM instrs/wave, 100% line
// utilization (lanes n=0..15 cover 256B contiguous per quad).
// Unpack order pr.u[d] identical to round 3 -> bit-identical results.
// ---------------------------------------------------------------------------
__global__ __launch_bounds__(384) void k_main(
    const float* __restrict__ hw, const unsigned* __restrict__ huP,
    const float* __restrict__ X, const int* __restrict__ mask,
    const float* __restrict__ Tx_w, const float* __restrict__ Tx_b,
    float* __restrict__ out)
{
    __shared__ unsigned TxP[16 * 130];   // [n][k2] bf16-pairs, stride 130
    __shared__ float m_lds[LDIM];
    __shared__ float part2[24 * 16 * 4]; // [g=w*4+quad][a][{s2x,s2y,s2z,s1}]
    __shared__ float part_m[24];

    const int i = blockIdx.x, b = blockIdx.y;
    const int tid = threadIdx.x;
    const int w = tid >> 6;              // wave 0..5
    const int lane = tid & 63;
    const int n = lane & 15;             // a-column / A-row-within-tile
    const int quad = lane >> 4;

    // ---- setup: Tx_w -> bf16 packed LDS; mask -> LDS
    for (int idx = tid; idx < 16 * 128; idx += 384) {
        const int nn = idx >> 7, k2 = idx & 127;
        unsigned v = 0;
        if (nn < ADIM) {
            const float2 tw = *(const float2*)&Tx_w[nn * HDIM + 2 * k2];
            v = pack_bf16(tw.x, tw.y);
        }
        TxP[nn * 130 + k2] = v;
    }
    m_lds[tid] = (float)mask[b * LDIM + tid];
    __syncthreads();

    const float* __restrict__ hwrow = &hw[(b * LDIM + i) * HDIM];
    const unsigned* __restrict__ hub = &huP[b * H2 * LDIM];  // grouped-of-4

    f32x4 acc[4];
    #pragma unroll
    for (int t = 0; t < 4; ++t) acc[t] = (f32x4){0.f, 0.f, 0.f, 0.f};

    const int jbase = w * 64 + n;        // A-side j for tile t: jbase + t*16

    #pragma unroll 2
    for (int kc = 0; kc < 8; ++kc) {
        // B-frag (shared across the 4 tiles): Tx_w[n][kc*32+quad*8 .. +7]
        union { unsigned u[4]; bf16x8 v; } bu;
        const int bofs = n * 130 + kc * 16 + quad * 4;
        *(uint2*)&bu.u[0] = *(const uint2*)&TxP[bofs];
        *(uint2*)&bu.u[2] = *(const uint2*)&TxP[bofs + 2];
        // hw values for this lane's k-slice (L1-resident row)
        const float4 hwa = *(const float4*)(hwrow + kc * 32 + quad * 8);
        const float4 hwb = *(const float4*)(hwrow + kc * 32 + quad * 8 + 4);
        const float hv[8] = {hwa.x, hwa.y, hwa.z, hwa.w, hwb.x, hwb.y, hwb.z, hwb.w};
        const int blkb = kc * 4 + quad;  // (h2base >> 2)
        #pragma unroll
        for (int t = 0; t < 4; ++t) {
            union { uint4 q; unsigned u[4]; } pr;
            pr.q = *(const uint4*)&hub[(blkb * LDIM + jbase + t * 16) * 4];
            union { unsigned u[4]; bf16x8 v; } au;
            #pragma unroll
            for (int d = 0; d < 4; ++d) {
                const unsigned pk = pr.u[d];
                const float lo = __uint_as_float(pk << 16);
                const float hi = __uint_as_float(pk & 0xffff0000u);
                const float t0 = fmaxf(hv[2 * d] + lo, 0.f);
                const float t1 = fmaxf(hv[2 * d + 1] + hi, 0.f);
                au.u[d] = pack_bf16(t0, t1);
            }
            acc[t] = __builtin_amdgcn_mfma_f32_16x16x32_bf16(au.v, bu.v, acc[t], 0, 0, 0);
        }
    }

    // ---- epilogue: per-lane partial sums over its 16 j's (a = n)
    float s1 = 0.f, s2x = 0.f, s2y = 0.f, s2z = 0.f, pm = 0.f;
    if (n < ADIM) {
        const float txb = Tx_b[n];
        #pragma unroll
        for (int t = 0; t < 4; ++t) {
            #pragma unroll
            for (int r = 0; r < 4; ++r) {
                const int jd = (w * 4 + t) * 16 + quad * 4 + r;
                const float m = m_lds[jd];
                const float g = acc[t][r] + txb;
                const float mg = m * g;
                const float* __restrict__ Xp = &X[((b * LDIM + jd) * ADIM + n) * 3];
                s1 += mg;
                s2x = fmaf(mg, Xp[0], s2x);
                s2y = fmaf(mg, Xp[1], s2y);
                s2z = fmaf(mg, Xp[2], s2z);
                pm += m;
            }
        }
    }
    {
        f32x4 sv = {s2x, s2y, s2z, s1};
        *(f32x4*)&part2[((w * 4 + quad) * 16 + n) * 4] = sv;
    }
    if (n == 0) part_m[w * 4 + quad] = pm;
    __syncthreads();

    if (tid < 42) {
        const int a = tid / 3, c = tid % 3;
        float S2 = 0.f, S1 = 0.f, msum = 0.f;
        #pragma unroll 4
        for (int g = 0; g < 24; ++g) {
            const float* __restrict__ p = &part2[(g * 16 + a) * 4];
            S2 += p[c]; S1 += p[3]; msum += part_m[g];
        }
        const float denom = 1e-6f + msum;
        const int idx = ((b * LDIM + i) * ADIM + a) * 3 + c;
        const float xi = X[idx];
        float f = (xi * S1 - S2) / denom;
        f = fminf(fmaxf(f, -20.f), 20.f);
        out[idx] = xi + f;
    }
}

extern "C" void kernel_launch(void* const* d_in, const int* in_sizes, int n_in,
                              void* d_out, int out_size, void* d_ws, size_t ws_size,
                              hipStream_t stream) {
    (void)in_sizes; (void)n_in; (void)out_size; (void)ws_size;
    const float* h    = (const float*)d_in[0];
    const float* X    = (const float*)d_in[1];
    const int*   mask = (const int*)  d_in[2];
    const float* Wx_w = (const float*)d_in[3];
    const float* Wx_b = (const float*)d_in[4];
    const float* Ux_w = (const float*)d_in[5];
    const float* Ux_b = (const float*)d_in[6];
    const float* Tx_w = (const float*)d_in[7];
    const float* Tx_b = (const float*)d_in[8];
    float* out = (float*)d_out;

    float*    hw  = (float*)d_ws;                         // B*L*H fp32
    unsigned* huP = (unsigned*)(hw + BDIM * LDIM * HDIM); // B*(H2*L) grouped-of-4

    k_gemm<<<dim3(16, 24), dim3(64), 0, stream>>>(h, Wx_w, Wx_b, Ux_w, Ux_b, hw, huP);
    k_main<<<dim3(LDIM, BDIM), 384, 0, stream>>>(hw, huP, X, mask, Tx_w, Tx_b, out);
}

// Round 10
// 86.596 us; speedup vs baseline: 1.4397x; 1.0794x over previous
//
#include <hip/hip_runtime.h>
#include <hip/hip_bf16.h>
#include <hip/hip_fp16.h>

#define HDIM 256
#define LDIM 384
#define BDIM 2
#define ADIM 14
#define H2 (HDIM / 2)

typedef __attribute__((ext_vector_type(8))) short bf16x8;
typedef __attribute__((ext_vector_type(8))) _Float16 f16x8;
typedef __attribute__((ext_vector_type(4))) float f32x4;

static __device__ __forceinline__ unsigned pack_bf16(float x, float y) {
    __hip_bfloat162 t = __float22bfloat162_rn(make_float2(x, y));  // x -> low 16
    return *reinterpret_cast<unsigned*>(&t);
}

static __device__ __forceinline__ unsigned pack_f16(float x, float y) {
    __half2 t = __floats2half2_rn(x, y);                           // x -> low 16
    return *reinterpret_cast<unsigned*>(&t);
}

static __device__ __forceinline__ bf16x8 cvt8(float4 a, float4 b) {
    union { unsigned u[4]; bf16x8 v; } r;
    r.u[0] = pack_bf16(a.x, a.y); r.u[1] = pack_bf16(a.z, a.w);
    r.u[2] = pack_bf16(b.x, b.y); r.u[3] = pack_bf16(b.z, b.w);
    return r.v;
}

// relu(a + b) on packed f16 pairs, via explicit VOP3P asm (avoids the
// bf16/f16 __hadd2/__hmax2 header overload clash on ROCm 7.2).
static __device__ __forceinline__ unsigned pk_addrelu_f16(unsigned a, unsigned b) {
    unsigned s, r;
    asm("v_pk_add_f16 %0, %1, %2" : "=v"(s) : "v"(a), "v"(b));
    asm("v_pk_max_f16 %0, %1, 0"  : "=v"(r) : "v"(s));
    return r;
}

// ---------------------------------------------------------------------------
// Kernel 1 (MFMA): C(512c x 768rows) = [Wx;Ux](512x256) x h^T, bf16 inputs,
// fp32 accum. One wave per 32c x 32row tile; grid (16 c-tiles, 24 row-tiles).
// Outputs (both packed f16 pairs — gate datapath is fp16):
//   c<256:  hwP[i][h2]  f16-pair packed, i-major (uint2 stores)
//   c>=256: huP grouped-of-4: hu[(h2>>2)*L*4 + j*4 + (h2&3)] (dwordx4 reads)
// ---------------------------------------------------------------------------
__global__ __launch_bounds__(64) void k_gemm(
    const float* __restrict__ h,
    const float* __restrict__ Wx_w, const float* __restrict__ Wx_b,
    const float* __restrict__ Ux_w, const float* __restrict__ Ux_b,
    unsigned* __restrict__ hwP, unsigned* __restrict__ huP)
{
    const int lane = threadIdx.x;
    const int n = lane & 15;             // D-col: row index within row-tile
    const int quad = lane >> 4;

    const int c0   = blockIdx.x * 32;    // channel base (0..480), within Wx or Ux
    const int row0 = blockIdx.y * 32;    // global row base (0..736), within one b

    const float* __restrict__ wbase = (c0 < HDIM) ? &Wx_w[c0 * HDIM]
                                                  : &Ux_w[(c0 - HDIM) * HDIM];
    const float* __restrict__ wl0 = wbase + (n) * HDIM + quad * 8;
    const float* __restrict__ wl1 = wbase + (16 + n) * HDIM + quad * 8;
    const float* __restrict__ hl0 = h + (row0 + n) * HDIM + quad * 8;
    const float* __restrict__ hl1 = h + (row0 + 16 + n) * HDIM + quad * 8;

    f32x4 acc00 = {0,0,0,0}, acc01 = {0,0,0,0}, acc10 = {0,0,0,0}, acc11 = {0,0,0,0};

    #pragma unroll 4
    for (int kc = 0; kc < 8; ++kc) {
        const int ko = kc * 32;
        const bf16x8 a0 = cvt8(*(const float4*)(wl0 + ko), *(const float4*)(wl0 + ko + 4));
        const bf16x8 a1 = cvt8(*(const float4*)(wl1 + ko), *(const float4*)(wl1 + ko + 4));
        const bf16x8 b0 = cvt8(*(const float4*)(hl0 + ko), *(const float4*)(hl0 + ko + 4));
        const bf16x8 b1 = cvt8(*(const float4*)(hl1 + ko), *(const float4*)(hl1 + ko + 4));
        acc00 = __builtin_amdgcn_mfma_f32_16x16x32_bf16(a0, b0, acc00, 0, 0, 0);
        acc01 = __builtin_amdgcn_mfma_f32_16x16x32_bf16(a0, b1, acc01, 0, 0, 0);
        acc10 = __builtin_amdgcn_mfma_f32_16x16x32_bf16(a1, b0, acc10, 0, 0, 0);
        acc11 = __builtin_amdgcn_mfma_f32_16x16x32_bf16(a1, b1, acc11, 0, 0, 0);
    }

    const int grow0 = row0 + n;
    const int grow1 = row0 + 16 + n;
    const int b = row0 / LDIM;           // uniform per block
    const int i0 = grow0 - b * LDIM, i1 = grow1 - b * LDIM;

    if (c0 < HDIM) {
        // hw: pack f16 pairs, i-major [i][h2]; lane holds 4 consecutive c
        #pragma unroll
        for (int ct = 0; ct < 2; ++ct) {
            const int cb = c0 + ct * 16 + quad * 4;
            const float4 bias = *(const float4*)&Wx_b[cb];
            const f32x4 aR0 = ct ? acc10 : acc00;
            const f32x4 aR1 = ct ? acc11 : acc01;
            const int h2 = cb >> 1;                            // even -> 8B aligned
            *(uint2*)&hwP[grow0 * H2 + h2] = make_uint2(
                pack_f16(aR0[0] + bias.x, aR0[1] + bias.y),
                pack_f16(aR0[2] + bias.z, aR0[3] + bias.w));
            *(uint2*)&hwP[grow1 * H2 + h2] = make_uint2(
                pack_f16(aR1[0] + bias.x, aR1[1] + bias.y),
                pack_f16(aR1[2] + bias.z, aR1[3] + bias.w));
        }
    } else {
        // hu: f16 pairs into grouped-of-4 layout
        unsigned* __restrict__ hub = &huP[b * H2 * LDIM];
        #pragma unroll
        for (int ct = 0; ct < 2; ++ct) {
            const int ch = (c0 - HDIM) + ct * 16 + quad * 4;   // multiple of 4
            const float4 bias = *(const float4*)&Ux_b[ch];
            const f32x4 aR0 = ct ? acc10 : acc00;
            const f32x4 aR1 = ct ? acc11 : acc01;
            const int h2  = ch >> 1;
            const int blk = h2 >> 2, off = h2 & 3;             // off in {0,2}
            *(uint2*)&hub[(blk * LDIM + i0) * 4 + off] = make_uint2(
                pack_f16(aR0[0] + bias.x, aR0[1] + bias.y),
                pack_f16(aR0[2] + bias.z, aR0[3] + bias.w));
            *(uint2*)&hub[(blk * LDIM + i1) * 4 + off] = make_uint2(
                pack_f16(aR1[0] + bias.x, aR1[1] + bias.y),
                pack_f16(aR1[2] + bias.z, aR1[3] + bias.w));
        }
    }
}

// ---------------------------------------------------------------------------
// Kernel 2: one block per (b,i) — 768 blocks, 3/CU, no barriers in the loop.
// gate = relu(hw_i + hu_j) @ Tx_w^T via f16 MFMA. A-frag build is packed f16:
// au.u[d] = v_pk_max_f16(v_pk_add_f16(hw_pk, hu_pk), 0) — 2 VALU per pair
// (was 7 on the bf16 path: shift, mask, 2 add, 2 max, cvt_pk).
// ---------------------------------------------------------------------------
__global__ __launch_bounds__(384) void k_main(
    const unsigned* __restrict__ hwP, const unsigned* __restrict__ huP,
    const float* __restrict__ X, const int* __restrict__ mask,
    const float* __restrict__ Tx_w, const float* __restrict__ Tx_b,
    float* __restrict__ out)
{
    __shared__ unsigned TxP[16 * 130];   // [n][k2] f16-pairs, stride 130
    __shared__ float m_lds[LDIM];
    __shared__ float part2[24 * 16 * 4]; // [g=w*4+quad][a][{s2x,s2y,s2z,s1}]
    __shared__ float part_m[24];

    const int i = blockIdx.x, b = blockIdx.y;
    const int tid = threadIdx.x;
    const int w = tid >> 6;              // wave 0..5
    const int lane = tid & 63;
    const int n = lane & 15;             // a-column / A-row-within-tile
    const int quad = lane >> 4;

    // ---- setup: Tx_w -> f16 packed LDS; mask -> LDS
    for (int idx = tid; idx < 16 * 128; idx += 384) {
        const int nn = idx >> 7, k2 = idx & 127;
        unsigned v = 0;
        if (nn < ADIM) {
            const float2 tw = *(const float2*)&Tx_w[nn * HDIM + 2 * k2];
            v = pack_f16(tw.x, tw.y);
        }
        TxP[nn * 130 + k2] = v;
    }
    m_lds[tid] = (float)mask[b * LDIM + tid];
    __syncthreads();

    const unsigned* __restrict__ hwrow = &hwP[(b * LDIM + i) * H2];
    const unsigned* __restrict__ hub = &huP[b * H2 * LDIM];  // grouped-of-4

    f32x4 acc[4];
    #pragma unroll
    for (int t = 0; t < 4; ++t) acc[t] = (f32x4){0.f, 0.f, 0.f, 0.f};

    const int jbase = w * 64 + n;        // A-side j for tile t: jbase + t*16

    #pragma unroll 2
    for (int kc = 0; kc < 8; ++kc) {
        // B-frag (shared across the 4 tiles): Tx_w[n][kc*32+quad*8 .. +7]
        union { unsigned u[4]; f16x8 v; } bu;
        const int bofs = n * 130 + kc * 16 + quad * 4;
        *(uint2*)&bu.u[0] = *(const uint2*)&TxP[bofs];
        *(uint2*)&bu.u[2] = *(const uint2*)&TxP[bofs + 2];
        // hw packed pairs for this lane's k-slice (one dwordx4, quad-broadcast)
        union { uint4 q; unsigned u[4]; } hwq;
        hwq.q = *(const uint4*)&hwrow[kc * 16 + quad * 4];
        const int blkb = kc * 4 + quad;  // (h2base >> 2)
        #pragma unroll
        for (int t = 0; t < 4; ++t) {
            union { uint4 q; unsigned u[4]; } pr;
            pr.q = *(const uint4*)&hub[(blkb * LDIM + jbase + t * 16) * 4];
            union { unsigned u[4]; f16x8 v; } au;
            #pragma unroll
            for (int d = 0; d < 4; ++d) {
                au.u[d] = pk_addrelu_f16(hwq.u[d], pr.u[d]);
            }
            acc[t] = __builtin_amdgcn_mfma_f32_16x16x32_f16(au.v, bu.v, acc[t], 0, 0, 0);
        }
    }

    // ---- epilogue: per-lane partial sums over its 16 j's (a = n)
    float s1 = 0.f, s2x = 0.f, s2y = 0.f, s2z = 0.f, pm = 0.f;
    if (n < ADIM) {
        const float txb = Tx_b[n];
        #pragma unroll
        for (int t = 0; t < 4; ++t) {
            #pragma unroll
            for (int r = 0; r < 4; ++r) {
                const int jd = (w * 4 + t) * 16 + quad * 4 + r;
                const float m = m_lds[jd];
                const float g = acc[t][r] + txb;
                const float mg = m * g;
                const float* __restrict__ Xp = &X[((b * LDIM + jd) * ADIM + n) * 3];
                s1 += mg;
                s2x = fmaf(mg, Xp[0], s2x);
                s2y = fmaf(mg, Xp[1], s2y);
                s2z = fmaf(mg, Xp[2], s2z);
                pm += m;
            }
        }
    }
    {
        f32x4 sv = {s2x, s2y, s2z, s1};
        *(f32x4*)&part2[((w * 4 + quad) * 16 + n) * 4] = sv;
    }
    if (n == 0) part_m[w * 4 + quad] = pm;
    __syncthreads();

    if (tid < 42) {
        const int a = tid / 3, c = tid % 3;
        float S2 = 0.f, S1 = 0.f, msum = 0.f;
        #pragma unroll 4
        for (int g = 0; g < 24; ++g) {
            const float* __restrict__ p = &part2[(g * 16 + a) * 4];
            S2 += p[c]; S1 += p[3]; msum += part_m[g];
        }
        const float denom = 1e-6f + msum;
        const int idx = ((b * LDIM + i) * ADIM + a) * 3 + c;
        const float xi = X[idx];
        float f = (xi * S1 - S2) / denom;
        f = fminf(fmaxf(f, -20.f), 20.f);
        out[idx] = xi + f;
    }
}

extern "C" void kernel_launch(void* const* d_in, const int* in_sizes, int n_in,
                              void* d_out, int out_size, void* d_ws, size_t ws_size,
                              hipStream_t stream) {
    (void)in_sizes; (void)n_in; (void)out_size; (void)ws_size;
    const float* h    = (const float*)d_in[0];
    const float* X    = (const float*)d_in[1];
    const int*   mask = (const int*)  d_in[2];
    const float* Wx_w = (const float*)d_in[3];
    const float* Wx_b = (const float*)d_in[4];
    const float* Ux_w = (const float*)d_in[5];
    const float* Ux_b = (const float*)d_in[6];
    const float* Tx_w = (const float*)d_in[7];
    const float* Tx_b = (const float*)d_in[8];
    float* out = (float*)d_out;

    unsigned* hwP = (unsigned*)d_ws;                // B*L*H2 packed f16 pairs (i-major)
    unsigned* huP = hwP + BDIM * LDIM * H2;         // B*(H2*L) grouped-of-4 f16 pairs

    k_gemm<<<dim3(16, 24), dim3(64), 0, stream>>>(h, Wx_w, Wx_b, Ux_w, Ux_b, hwP, huP);
    k_main<<<dim3(LDIM, BDIM), 384, 0, stream>>>(hwP, huP, X, mask, Tx_w, Tx_b, out);
}